// Round 1
// 10694.050 us; speedup vs baseline: 1.0313x; 1.0313x over previous
//
#include <hip/hip_runtime.h>

// ZoneoutGRU persistent kernel v8: B=64, T=1024, IN=512, H=1024, L=2, zo=0.1.
// 128 active blocks (64 LA = layer0, 64 LB = layer1), 256 thr (4 waves = K
// slices). Weights VGPR-resident, fp32 h state in registers. Sync protocol
// v3/v4 (proven): relaxed agent atomics only, no fences in loop. Deep h rings
// (v7): consumer reads are L2-cacheable (sc0), no stale-L2 hazard.
// v8 vs v7: DVFS experiment. Counter arithmetic (MfmaUtil 5.2% over 88M MFMAs)
// implies effective SCLK ~730 MHz — the chip idles in a low DPM state because
// ~95% of waves are asleep (s_sleep pollers + barrier-parked waves) and blocks
// 128..255 exit immediately. v8 turns the 128 pad blocks into busy VALU
// spinners (4 indep FMA chains, no memory traffic except a 1-line completion
// poll every ~2k cycles) to hold SCLK up. Active-block code path is UNCHANGED.

#define Tn 1024
#define Hn 1024
#define INn 512

typedef short s8v __attribute__((ext_vector_type(8)));
typedef float f4v __attribute__((ext_vector_type(4)));
typedef unsigned short us4v __attribute__((ext_vector_type(4)));
typedef unsigned long long ull;

// ws layout (bytes) — total 168,837,120 (~161 MB)
#define WS_XB  0u           // x bf16 [64][1024][512]            = 67,108,864
#define WS_H0R 67108864u    // ring [512][ktile64][b64][16] bf16 = 67,108,864
#define WS_H1R 134217728u   // ring [256][ktile64][b64][16] bf16 = 33,554,432
#define WS_CA  167772160u   // [1040][128] int (8 banks @ 64B)   =    532,480
#define WS_CB  168304640u   // same                              =    532,480

__device__ __forceinline__ unsigned short f2bf(float f) {
  unsigned int u = __float_as_uint(f);
  u += 0x7fffu + ((u >> 16) & 1u);
  return (unsigned short)(u >> 16);
}

__device__ __forceinline__ s8v pack8(const float* p) {
  float4 a = *(const float4*)p;
  float4 b = *(const float4*)(p + 4);
  s8v r;
  r[0] = (short)f2bf(a.x); r[1] = (short)f2bf(a.y);
  r[2] = (short)f2bf(a.z); r[3] = (short)f2bf(a.w);
  r[4] = (short)f2bf(b.x); r[5] = (short)f2bf(b.y);
  r[6] = (short)f2bf(b.z); r[7] = (short)f2bf(b.w);
  return r;
}

// producer store: relaxed agent-scope 8B atomic = write-through to MALL (v3+)
__device__ __forceinline__ void st8c(unsigned short* p, us4v v) {
  union { us4v v; ull u; } c; c.v = v;
  __hip_atomic_store((ull*)p, c.u, __ATOMIC_RELAXED, __HIP_MEMORY_SCOPE_AGENT);
}

// consumer loads: sc0 only — L1-bypass, L2-CACHEABLE (deep ring => no stale)
__device__ __forceinline__ void issue4c(s8v* f, const unsigned short* src,
                                        int kt, int w, int rl, int kg) {
#pragma unroll
  for (int m = 0; m < 4; ++m) {
    const unsigned short* p = src + (size_t)(w * 16 + kt * 2 + (kg >> 1)) * 1024
                              + (m * 16 + rl) * 16 + (kg & 1) * 8;
    asm volatile("global_load_dwordx4 %0, %1, off sc0"
                 : "=v"(f[m]) : "v"(p) : "memory");
  }
}

#define VMWAIT(n) do { asm volatile("s_waitcnt vmcnt(" #n ")" ::: "memory"); \
                       __builtin_amdgcn_sched_barrier(0); } while (0)

__device__ __forceinline__ void mfma3(f4v (*acc)[4], s8v w0, s8v w1, s8v w2,
                                      const s8v f[4], const int gl) {
#pragma unroll
  for (int m = 0; m < 4; ++m) {
    acc[m][0]  = __builtin_amdgcn_mfma_f32_16x16x32_bf16(w0, f[m], acc[m][0], 0, 0, 0);
    acc[m][1]  = __builtin_amdgcn_mfma_f32_16x16x32_bf16(w1, f[m], acc[m][1], 0, 0, 0);
    acc[m][gl] = __builtin_amdgcn_mfma_f32_16x16x32_bf16(w2, f[m], acc[m][gl], 0, 0, 0);
  }
}

// v4-proven 2-deep pipelined stream GEMM: 8 k-tiles, fA/fB alternation
template<int GL>
__device__ __forceinline__ void stream_gemm(f4v (*acc)[4], const s8v (*wgt)[8],
    const unsigned short* src, int w, int rl, int kg) {
  s8v fA[4], fB[4];
  issue4c(fA, src, 0, w, rl, kg);
#pragma unroll
  for (int kt = 0; kt < 8; kt += 2) {
    issue4c(fB, src, kt + 1, w, rl, kg);
    VMWAIT(4);                              // fA complete (fB outstanding)
    mfma3(acc, wgt[0][kt], wgt[1][kt], wgt[2][kt], fA, GL);
    if (kt + 2 < 8) {
      issue4c(fA, src, kt + 2, w, rl, kg);
      VMWAIT(4);                            // fB complete (fA outstanding)
    } else {
      VMWAIT(0);                            // drain
    }
    mfma3(acc, wgt[0][kt + 1], wgt[1][kt + 1], wgt[2][kt + 1], fB, GL);
  }
}

__global__ void cvt_bf16_kernel(const float* __restrict__ src,
                                unsigned short* __restrict__ dst, int n4) {
  int i = blockIdx.x * blockDim.x + threadIdx.x;
  int st = gridDim.x * blockDim.x;
  for (; i < n4; i += st) {
    const float4 v = *(const float4*)(src + 4 * (size_t)i);
    us4v o;
    o[0] = f2bf(v.x); o[1] = f2bf(v.y); o[2] = f2bf(v.z); o[3] = f2bf(v.w);
    *(us4v*)(dst + 4 * (size_t)i) = o;
  }
}

__global__ void init_all(const float* __restrict__ h0in, char* __restrict__ ws) {
  int i = blockIdx.x * blockDim.x + threadIdx.x;   // grid 528*256 = 135168
  unsigned short* h0r = (unsigned short*)(ws + WS_H0R);
  unsigned short* h1r = (unsigned short*)(ws + WS_H1R);
  int* CA = (int*)(ws + WS_CA);
  int* CB = (int*)(ws + WS_CB);
  if (i < 65536) {
    int b = i >> 10, h = i & 1023;
    int off = (h >> 4) * 1024 + b * 16 + (h & 15);
    h0r[511 * 65536 + off] = f2bf(h0in[i]);          // slot for step -1
    h1r[255 * 65536 + off] = f2bf(h0in[65536 + i]);  // slot for step -1
  }
  if (i < 133120) {
    int v = ((i >> 7) < 16 && (i & 15) == 0) ? 8 : 0;
    CA[i] = v; CB[i] = v;
  }
}

__device__ __forceinline__ void spin_ge(int* p, int target) {
  int tries = 0;
  while (__hip_atomic_load(p, __ATOMIC_RELAXED, __HIP_MEMORY_SCOPE_AGENT) < target) {
    __builtin_amdgcn_s_sleep(1);
    if (++tries > (1 << 22)) break;   // fail visibly, never hang
  }
}

// counter dword index for step s (>= -16), bank k
#define CDW(s, k) (((s) + 16) * 128 + (k) * 16)

__global__ __launch_bounds__(256, 1) void gru_persist(
    const float* __restrict__ h0in,
    const float* __restrict__ wih0, const float* __restrict__ whh0,
    const float* __restrict__ bih0, const float* __restrict__ bhh0,
    const float* __restrict__ wih1, const float* __restrict__ whh1,
    const float* __restrict__ bih1, const float* __restrict__ bhh1,
    float* __restrict__ out, char* __restrict__ ws)
{
  const unsigned short* xb = (const unsigned short*)(ws + WS_XB);
  unsigned short* h0r = (unsigned short*)(ws + WS_H0R);
  unsigned short* h1r = (unsigned short*)(ws + WS_H1R);
  int* CA = (int*)(ws + WS_CA);
  int* CB = (int*)(ws + WS_CB);

  const int blk = blockIdx.x;
  const int tid = threadIdx.x;

  if (blk >= 128) {
    // v8: busy-clock pad. Keep SCLK/DPM high while active blocks handshake.
    // 4 independent dependent-FMA chains => full VALU issue rate, no memory
    // traffic except tid0's single-counter-line completion poll per ~2k cyc.
    __shared__ int sdone;
    if (tid == 0) sdone = 0;
    __syncthreads();
    float a0 = 1.0f + (float)tid * 1e-6f, a1 = a0 + 0.25f;
    float a2 = a0 + 0.5f, a3 = a0 + 0.75f;
    const float m = 0.99999988f, c = 1e-7f;
    int kcur = 0;
    for (int it = 0; it < (1 << 18) && kcur < 8; ++it) {
#pragma unroll
      for (int u = 0; u < 256; ++u) {
        a0 = __builtin_fmaf(a0, m, c); a1 = __builtin_fmaf(a1, m, c);
        a2 = __builtin_fmaf(a2, m, c); a3 = __builtin_fmaf(a3, m, c);
      }
      if (tid == 0 &&
          __hip_atomic_load(&CB[CDW(Tn - 1, kcur)], __ATOMIC_RELAXED,
                            __HIP_MEMORY_SCOPE_AGENT) >= 8)
        sdone = kcur + 1;
      __syncthreads();
      kcur = sdone;        // uniform across the block
      __syncthreads();     // protect sdone write of next iteration
    }
    asm volatile("" :: "v"(a0), "v"(a1), "v"(a2), "v"(a3));  // keep chains live
    return;
  }

  const bool isA = blk < 64;
  const int jt = blk & 63, jj = jt * 16;
  const int w = tid >> 6;                    // wave = K-slice = owner m-group
  const int lane = tid & 63;
  const int rl = lane & 15, kg = lane >> 4;
  const int bank = blk & 7;

  __shared__ float cmb[4][4][64][20];        // stride 80B: conflict-free (r6)

  const int b = w * 16 + rl;                 // owner batch row (epilogue)
  const int j0 = jj + kg * 4;                // owner j base (epilogue)

  // ---- VGPR-resident weights ----
  const float* Wi = isA ? wih0 : wih1;
  const float* Wh = isA ? whh0 : whh1;
  const float* bi = isA ? bih0 : bih1;
  const float* bh = isA ? bhh0 : bhh1;
  const int Kx = isA ? INn : Hn;             // input-side K
  s8v wx[3][8], wh_[3][8];
  const int nkx = Kx / 128;                  // 4 (LA) or 8 (LB) k-tiles of 32
#pragma unroll
  for (int g = 0; g < 3; ++g) {
    for (int kt = 0; kt < nkx; ++kt)
      wx[g][kt] = pack8(Wi + (size_t)(g * 1024 + jj + rl) * Kx + w * (Kx / 4) + kt * 32 + kg * 8);
#pragma unroll
    for (int kt = 0; kt < 8; ++kt)
      wh_[g][kt] = pack8(Wh + (size_t)(g * 1024 + jj + rl) * Hn + w * 256 + kt * 32 + kg * 8);
  }
  const f4v bir = *(const f4v*)(bi + j0),        bhr = *(const f4v*)(bh + j0);
  const f4v biz = *(const f4v*)(bi + 1024 + j0), bhz = *(const f4v*)(bh + 1024 + j0);
  const f4v bin = *(const f4v*)(bi + 2048 + j0), bhn = *(const f4v*)(bh + 2048 + j0);

  // ---- register-resident fp32 hidden state (this thread's (b, j0..j0+3)) ----
  f4v hv = *(const f4v*)(h0in + (isA ? 0u : 65536u) + (size_t)b * Hn + j0);

  for (int s = 0; s < Tn; ++s) {
    // 1. LA: prefetch x fragments (plain cached loads, v4-proven) before spin
    s8v bx[4][4];
    if (isA) {
#pragma unroll
      for (int m = 0; m < 4; ++m)
#pragma unroll
        for (int kt = 0; kt < 4; ++kt)
          bx[m][kt] = *(const s8v*)(xb + ((size_t)(m * 16 + rl) * Tn + s) * INn + w * 128 + kt * 32 + kg * 8);
    }
    // 2. spin on banked counters (8 parallel pollers each; relaxed, MALL)
    if (isA) {
      if (tid < 8)                      spin_ge(&CA[CDW(s - 1, tid)], 8);
      else if (tid < 16 && s >= 256)    spin_ge(&CB[CDW(s - 256, tid - 8)], 8);
    } else {
      if (tid < 8)                      spin_ge(&CA[CDW(s, tid)], 8);
      else if (tid < 16)                spin_ge(&CB[CDW(s - 1, tid - 8)], 8);
    }
    __syncthreads();
    VMWAIT(0);                               // clean baseline for counted pipe

    f4v acc[4][4];
#pragma unroll
    for (int m = 0; m < 4; ++m)
#pragma unroll
      for (int g = 0; g < 4; ++g) acc[m][g] = (f4v){0.f, 0.f, 0.f, 0.f};

    // deep-ring slots (no address reuse within 256+ steps => L2-cache safe)
    const unsigned short* hsrc = isA ? (h0r + (size_t)((s - 1) & 511) * 65536)
                                     : (h1r + (size_t)((s - 1) & 255) * 65536);
    const unsigned short* asrc = h0r + (size_t)(s & 511) * 65536;  // LB input h0[s]

    if (isA) {
      // 3a. x-GEMM from registers
#pragma unroll
      for (int kt = 0; kt < 4; ++kt) {
        s8v f4[4] = { bx[0][kt], bx[1][kt], bx[2][kt], bx[3][kt] };
        mfma3(acc, wx[0][kt], wx[1][kt], wx[2][kt], f4, 2);
      }
      // 3b. hidden stream (L2-cached reads, 2-deep proven pipeline)
      stream_gemm<3>(acc, wh_, hsrc, w, rl, kg);
    } else {
      // 3. a-stream then h-stream (both L2-cached)
      stream_gemm<2>(acc, wx, asrc, w, rl, kg);
      VMWAIT(0);
      stream_gemm<3>(acc, wh_, hsrc, w, rl, kg);
    }

    // 4. cross-wave K-combine (LDS)
#pragma unroll
    for (int d = 0; d < 4; ++d) if (d != w)
#pragma unroll
      for (int g = 0; g < 4; ++g) *(f4v*)&cmb[d][w][lane][g * 4] = acc[d][g];
    __syncthreads();
    f4v hsum[4];
#pragma unroll
    for (int g = 0; g < 4; ++g) {
      hsum[g] = acc[w][g];
#pragma unroll
      for (int src = 0; src < 4; ++src) if (src != w) hsum[g] += *(f4v*)&cmb[w][src][lane][g * 4];
    }

    // 5. epilogue: gates + zoneout, state stays in hv registers
    us4v hb4;
#pragma unroll
    for (int rr = 0; rr < 4; ++rr) {
      float hp = hv[rr];
      float rg = 1.f / (1.f + __expf(-(hsum[0][rr] + bir[rr] + bhr[rr])));
      float zg = 1.f / (1.f + __expf(-(hsum[1][rr] + biz[rr] + bhz[rr])));
      float narg = hsum[2][rr] + bin[rr] + rg * (hsum[3][rr] + bhn[rr]);
      float e2 = __expf(2.f * narg);
      float ng = 1.f - 2.f / (e2 + 1.f);
      float nv = (1.f - zg) * ng + zg * hp;
      hv[rr] = 0.1f * hp + 0.9f * nv;
    }
    hb4[0] = f2bf(hv[0]); hb4[1] = f2bf(hv[1]); hb4[2] = f2bf(hv[2]); hb4[3] = f2bf(hv[3]);

    // 6. broadcast bf16 h (write-through 8B atomics to deep ring), outputs (nt)
    if (isA) {
      st8c(h0r + (size_t)(s & 511) * 65536 + jt * 1024 + b * 16 + kg * 4, hb4);
      if (s == Tn - 1)
        __builtin_nontemporal_store(hv, (f4v*)(out + 67108864u + (size_t)b * Hn + j0));
    } else {
      st8c(h1r + (size_t)(s & 255) * 65536 + jt * 1024 + b * 16 + kg * 4, hb4);
      __builtin_nontemporal_store(hv, (f4v*)(out + ((size_t)b * Tn + s) * Hn + j0));
      if (s == Tn - 1)
        __builtin_nontemporal_store(hv, (f4v*)(out + 67108864u + 65536u + (size_t)b * Hn + j0));
    }
    // 7. drain stores to coherence point, then relaxed flag add
    asm volatile("s_waitcnt vmcnt(0)" ::: "memory");
    __syncthreads();
    if (tid == 0) {
      int* C = isA ? CA : CB;
      __hip_atomic_fetch_add(&C[CDW(s, bank)], 1, __ATOMIC_RELAXED, __HIP_MEMORY_SCOPE_AGENT);
    }
  }
}

extern "C" void kernel_launch(void* const* d_in, const int* in_sizes, int n_in,
                              void* d_out, int out_size, void* d_ws, size_t ws_size,
                              hipStream_t stream) {
  (void)in_sizes; (void)n_in; (void)out_size; (void)ws_size;
  const float* x    = (const float*)d_in[0];
  const float* h0in = (const float*)d_in[1];
  const float* wih0 = (const float*)d_in[2];
  const float* whh0 = (const float*)d_in[3];
  const float* bih0 = (const float*)d_in[4];
  const float* bhh0 = (const float*)d_in[5];
  const float* wih1 = (const float*)d_in[6];
  const float* whh1 = (const float*)d_in[7];
  const float* bih1 = (const float*)d_in[8];
  const float* bhh1 = (const float*)d_in[9];
  float* out = (float*)d_out;
  char* ws = (char*)d_ws;

  cvt_bf16_kernel<<<2048, 256, 0, stream>>>(x, (unsigned short*)(ws + WS_XB), 33554432 / 4);
  init_all<<<528, 256, 0, stream>>>(h0in, ws);
  gru_persist<<<dim3(256), dim3(256), 0, stream>>>(
      h0in, wih0, whh0, bih0, bhh0, wih1, whh1, bih1, bhh1, out, ws);
}